// Round 5
// baseline (581.910 us; speedup 1.0000x reference)
//
#include <hip/hip_runtime.h>
#include <hip/hip_cooperative_groups.h>

namespace cg = cooperative_groups;

// ---------------------------------------------------------------------------
// AMM chain, round 5: single cooperative mega-kernel, grid 256 x 512 thr.
// Phases (grid.sync between): conv | C1[q|betas2] | betas(Ksplit) | yb(RSA+
// Ksplit) | z0(RSA,soft) | 4x{ c(Ksplit) | zup(RSA) } | final.
// All GEMM phases full-grid-256, 64x64 tiles, 8 waves (2x2x2 M/N/Ksplit),
// fp16 MFMA f32-accum, XOR-swizzled LDS, counted-vmcnt pipelines.
// RSA = A-operand reg-staged from two f32 K-split partials (sum+cvt+ds_write).
// Workspace: 37 MB.
// ---------------------------------------------------------------------------

typedef _Float16 f16x8 __attribute__((ext_vector_type(8)));
typedef _Float16 f16x4 __attribute__((ext_vector_type(4)));
typedef float f32x4 __attribute__((ext_vector_type(4)));

enum { EPI_SPLIT, EPI_PART, EPI_SOFT, EPI_ZUP, EPI_FINAL };

typedef const __attribute__((address_space(1))) void* gas_ptr;
typedef __attribute__((address_space(3))) void* las_ptr;

__device__ __forceinline__ void gload16(const void* g, void* l) {
  __builtin_amdgcn_global_load_lds((gas_ptr)g, (las_ptr)l, 16, 0, 0);
}

__device__ __forceinline__ float softt(float t) {
  float s = fabsf(t) - 1.0f;
  s = s > 0.0f ? s : 0.0f;
  return copysignf(s, t);
}

struct KP {
  const float *x, *ke, *ve, *k0, *v0, *s0, *k1, *v1, *s1;
  float* out;
  _Float16* ws;
};

__device__ __forceinline__ void map32(int b, int& br, int& bc) {
  int x = b & 7, i = b >> 3;          // same-bcol blocks share an XCD
  bc = (x << 2) | (i & 3);
  br = i >> 2;
}
__device__ __forceinline__ void map16(int b, int& br, int& bc, int& hf) {
  int x = b & 7, i = b >> 3;
  bc = (x << 1) | (i & 1);
  int r = i >> 1;
  br = r & 7;
  hf = r >> 3;
}

#define LR(t)                                  \
  r0 = *(const float4*)(ap0 + ((t) << 6));     \
  r1 = *(const float4*)(ap0 + ((t) << 6) + 4); \
  r2 = *(const float4*)(ap1 + ((t) << 6));     \
  r3 = *(const float4*)(ap1 + ((t) << 6) + 4);

#define WRA(bf)                                                         \
  {                                                                     \
    f16x8 hv = {(_Float16)(r0.x + r2.x), (_Float16)(r0.y + r2.y),       \
                (_Float16)(r0.z + r2.z), (_Float16)(r0.w + r2.w),       \
                (_Float16)(r1.x + r3.x), (_Float16)(r1.y + r3.y),       \
                (_Float16)(r1.z + r3.z), (_Float16)(r1.w + r3.w)};      \
    *(f16x8*)(sm + (bf)*4096 + ldst + (lane << 3)) = hv;                \
  }

#define CMP(Ab, Bb)                                                           \
  {                                                                           \
    f16x8 av0 = *(const f16x8*)((Ab) + raddr0);                               \
    f16x8 av1 = *(const f16x8*)((Ab) + raddr1);                               \
    f16x8 bv0 = *(const f16x8*)((Bb) + baddr0);                               \
    f16x8 bv1 = *(const f16x8*)((Bb) + baddr1);                               \
    acc[0][0] =                                                               \
        __builtin_amdgcn_mfma_f32_16x16x32_f16(av0, bv0, acc[0][0], 0, 0, 0); \
    acc[0][1] =                                                               \
        __builtin_amdgcn_mfma_f32_16x16x32_f16(av0, bv1, acc[0][1], 0, 0, 0); \
    acc[1][0] =                                                               \
        __builtin_amdgcn_mfma_f32_16x16x32_f16(av1, bv0, acc[1][0], 0, 0, 0); \
    acc[1][1] =                                                               \
        __builtin_amdgcn_mfma_f32_16x16x32_f16(av1, bv1, acc[1][1], 0, 0, 0); \
  }

// ---------------------------------------------------------------------------
// One 64x64 output tile: C[m,n] = sum_k A[m,k]*B[n,k] (+ epilogue).
// RSA=false: A,B f16, 5-buffer gload_lds pipeline (vmcnt 6/4/2/0).
// RSA=true : A = pA0+pA1 (f32 partials, stride 1024), reg-staged; B gload;
//            3 A-bufs + 5 B-bufs, counted vmcnt, 1 barrier/K-step.
// ---------------------------------------------------------------------------
template <int EPI, bool RSA>
__device__ __forceinline__ void gtile(
    const _Float16* __restrict__ A, int lda, const _Float16* __restrict__ B,
    int ldb, int kbase, int nK, int N, int brow, int bcol,
    const float* __restrict__ pA0, const float* __restrict__ pA1,
    float* __restrict__ z0f, float* __restrict__ zf, float* __restrict__ exf,
    _Float16* __restrict__ oh, _Float16* __restrict__ oh2,
    float* __restrict__ ofin, _Float16* sm, int tid) {
  const int lane = tid & 63;
  const int w = tid >> 6;
  const int wr = (w >> 1) & 1, wc = w & 1, wk = w >> 2;
  const int srow = lane >> 3;
  const int scol = ((lane & 7) ^ srow) << 3;  // pre-swizzled source chunk
  const int a15 = lane & 15, hi = lane >> 4, l7 = lane & 7;
  const int ldst = w << 9;
  const _Float16* bpg =
      B + (size_t)(bcol + (w << 3) + srow) * ldb + kbase + scol;

  int raddr0, raddr1, baddr0, baddr1;
  {
    int ca = ((wk << 2) + hi) ^ l7;
    int ra = (wr << 5) + a15;
    raddr0 = ra * 64 + (ca << 3);
    raddr1 = (ra + 16) * 64 + (ca << 3);
    int rb = (wc << 5) + a15;
    baddr0 = rb * 64 + (ca << 3);
    baddr1 = (rb + 16) * 64 + (ca << 3);
  }

  f32x4 acc[2][2] = {};

  __syncthreads();  // previous phase done with LDS

  if constexpr (!RSA) {
    const _Float16* apg =
        A + (size_t)(brow + (w << 3) + srow) * lda + kbase + scol;
#pragma unroll
    for (int p = 0; p < 3; ++p) {
      gload16(apg + (p << 6), sm + p * 4096 + ldst);
      gload16(bpg + (p << 6), sm + 20480 + p * 4096 + ldst);
    }
    int bi = 0, bs = 3;
    for (int kt = 0; kt < nK; ++kt) {
      if (kt + 3 < nK) {
        gload16(apg + ((kt + 3) << 6), sm + bs * 4096 + ldst);
        gload16(bpg + ((kt + 3) << 6), sm + 20480 + bs * 4096 + ldst);
      }
      const int rem = nK - 1 - kt;
      if (rem >= 3)
        asm volatile("s_waitcnt vmcnt(6)" ::: "memory");
      else if (rem == 2)
        asm volatile("s_waitcnt vmcnt(4)" ::: "memory");
      else if (rem == 1)
        asm volatile("s_waitcnt vmcnt(2)" ::: "memory");
      else
        asm volatile("s_waitcnt vmcnt(0)" ::: "memory");
      __builtin_amdgcn_s_barrier();
      __builtin_amdgcn_sched_barrier(0);
      CMP(sm + bi * 4096, sm + 20480 + bi * 4096)
      bi = bi == 4 ? 0 : bi + 1;
      bs = bs == 4 ? 0 : bs + 1;
    }
  } else {
    const size_t arow = (size_t)(brow + (w << 3) + srow);
    const float* ap0 = pA0 + arow * 1024 + kbase + scol;
    const float* ap1 = pA1 + arow * 1024 + kbase + scol;
    float4 r0, r1, r2, r3;
    // prologue: A(0) via regs, B(0..2) via gload
    LR(0)
    gload16(bpg, sm + 12288 + ldst);
    gload16(bpg + 64, sm + 12288 + 4096 + ldst);
    gload16(bpg + 128, sm + 12288 + 2 * 4096 + ldst);
    asm volatile("s_waitcnt vmcnt(3)" ::: "memory");  // LR(0) done
    WRA(0)
    LR(1)
    asm volatile("s_waitcnt vmcnt(6)" ::: "memory");  // B(0) done
    asm volatile("s_waitcnt lgkmcnt(0)" ::: "memory");
    __builtin_amdgcn_s_barrier();
    __builtin_amdgcn_sched_barrier(0);
    int ai = 0, bi = 0, aw = 1, bs = 3;
    for (int kt = 0; kt < nK; ++kt) {
      CMP(sm + ai * 4096, sm + 12288 + bi * 4096)
      if (kt == nK - 1) break;
      if (kt + 3 < nK) {
        gload16(bpg + ((kt + 3) << 6), sm + 12288 + bs * 4096 + ldst);
        asm volatile("s_waitcnt vmcnt(1)" ::: "memory");  // rc(kt+1) ready
      } else {
        asm volatile("s_waitcnt vmcnt(0)" ::: "memory");
      }
      WRA(aw)
      if (kt + 2 < nK) { LR(kt + 2) }
      asm volatile("s_waitcnt lgkmcnt(0)" ::: "memory");  // WRA visible
      __builtin_amdgcn_s_barrier();
      __builtin_amdgcn_sched_barrier(0);
      ai = ai == 2 ? 0 : ai + 1;
      aw = aw == 2 ? 0 : aw + 1;
      bi = bi == 4 ? 0 : bi + 1;
      bs = bs == 4 ? 0 : bs + 1;
    }
  }

  // cross-K reduction (wk halves) through LDS f32 scratch
  __syncthreads();
  float* scr = (float*)sm;
  const int rbase = ((w & 3) * 64 + lane) << 4;
  if (wk == 1) {
#pragma unroll
    for (int mi = 0; mi < 2; ++mi)
#pragma unroll
      for (int ni = 0; ni < 2; ++ni)
        *(f32x4*)(scr + rbase + ((mi * 2 + ni) << 2)) = acc[mi][ni];
  }
  __syncthreads();
  if (wk == 0) {
#pragma unroll
    for (int mi = 0; mi < 2; ++mi)
#pragma unroll
      for (int ni = 0; ni < 2; ++ni) {
        acc[mi][ni] += *(const f32x4*)(scr + rbase + ((mi * 2 + ni) << 2));
#pragma unroll
        for (int r = 0; r < 4; ++r) {
          const int row = brow + (wr << 5) + (mi << 4) + (hi << 2) + r;
          const int col = bcol + (wc << 5) + (ni << 4) + a15;
          const float v = acc[mi][ni][r];
          if constexpr (EPI == EPI_SPLIT) {
            if (col < 1024)
              oh[(size_t)row * 1024 + col] = (_Float16)v;
            else
              oh2[(size_t)row * 1024 + (col - 1024)] = (_Float16)v;
          } else if constexpr (EPI == EPI_PART) {
            exf[(size_t)row * 1024 + col] = v;
          } else if constexpr (EPI == EPI_SOFT) {
            const size_t idx = (size_t)row * 2048 + col;
            z0f[idx] = v;
            float s = softt(v);
            zf[idx] = s;
            oh[idx] = (_Float16)s;
          } else if constexpr (EPI == EPI_ZUP) {
            const size_t idx = (size_t)row * 2048 + col;
            float t = z0f[idx] + zf[idx] - v;
            float s = softt(t);
            zf[idx] = s;
            oh[idx] = (_Float16)s;
          } else {  // EPI_FINAL
            const size_t idx = (size_t)row * 2048 + col;
            ofin[idx] = zf[idx] + v;
          }
        }
      }
  }
}

// ---------------------------------------------------------------------------
__global__ __launch_bounds__(512) void mega(KP p) {
  __shared__ __align__(16) _Float16 sm[40960];  // 80 KB
  cg::grid_group g = cg::this_grid();
  const int tid = threadIdx.x;
  const int bid = blockIdx.x;
  constexpr int MB1 = 1 << 20;
  _Float16* ws = p.ws;
  _Float16* ve_h = ws;                              // Ve natural (2048x1024)
  _Float16* ve_hT = ws + 2 * MB1;                   // Ve^T (1024x2048)
  _Float16* vt1_h = ws + 4 * MB1;                   // vals_t1 (2048x1024)
  _Float16* Bcat = ws + 6 * MB1;                    // [Ke^T; K1^T s1] 2048x2048
  float* z_f = (float*)(ws + 6 * MB1);              // overlay (post-C1)
  _Float16* zh = ws + 8 * MB1;                      // overlay (post-C1)
  _Float16* x_h = ws + 10 * MB1;                    // x f16
  _Float16* q_h = ws + 11 * MB1;                    // q f16
  float* z0_f = (float*)(ws + 10 * MB1);            // overlay (post-betas)
  _Float16* be2_h = ws + 12 * MB1;                  // betas2
  _Float16* kt0r = ws + 12 * MB1 + 524288;          // K0 row-scaled (1024x1024)
  _Float16* vt0T = ws + 13 * MB1 + 524288;          // V0^T
  float* Pa0 = (float*)(ws + 14 * MB1 + 524288);    // partials A (512x1024 f32)
  float* Pa1 = (float*)(ws + 15 * MB1 + 524288);
  float* Pb0 = (float*)(ws + 16 * MB1 + 524288);
  float* Pb1 = (float*)(ws + 17 * MB1 + 524288);

  // ---- phase 0: conversions ----
  {
    const int nx = 262144, nv = 524288, n1 = 524288, n0 = 262144;
    for (int i = bid * 512 + tid; i < nx + nv + n1 + n0; i += 256 * 512) {
      int j = i;
      const float4* s;
      f16x4* d;
      float sc = 1.0f;
      if (j < nx) {
        s = (const float4*)p.x; d = (f16x4*)x_h;
      } else if ((j -= nx) < nv) {
        s = (const float4*)p.ve; d = (f16x4*)ve_h;
      } else if ((j -= nv) < n1) {
        s = (const float4*)p.v1; d = (f16x4*)vt1_h;
      } else {
        j -= n1; s = (const float4*)p.k0; d = (f16x4*)kt0r; sc = p.s0[j >> 8];
      }
      float4 v = s[j];
      f16x4 h = {(_Float16)(v.x * sc), (_Float16)(v.y * sc),
                 (_Float16)(v.z * sc), (_Float16)(v.w * sc)};
      d[j] = h;
    }
  }
  {  // transposing converts: 7168 tiles of 32x32 = 28 iters/block (uniform)
    float(*t)[33] = (float(*)[33])sm;
    const int r = tid >> 5, tx = tid & 31;
    for (int jt = bid; jt < 7168; jt += 256) {
      const float* in;
      _Float16* out;
      const float* sv = nullptr;
      int R, lt;
      if (jt < 2048) {
        in = p.ke; out = Bcat; R = 2048; lt = jt;
      } else if (jt < 4096) {
        in = p.k1; out = Bcat + 2 * MB1; R = 2048; lt = jt - 2048; sv = p.s1;
      } else if (jt < 5120) {
        in = p.v0; out = vt0T; R = 1024; lt = jt - 4096;
      } else {
        in = p.ve; out = ve_hT; R = 2048; lt = jt - 5120;
      }
      const int c0 = (lt & 31) << 5;
      const int r0 = (lt >> 5) << 5;
      __syncthreads();
      t[r][tx] = in[(size_t)(r0 + r) * 1024 + c0 + tx];
      t[r + 16][tx] = in[(size_t)(r0 + r + 16) * 1024 + c0 + tx];
      __syncthreads();
      float va = t[tx][r], vb = t[tx][r + 16];
      if (sv) {
        va *= sv[c0 + r];
        vb *= sv[c0 + r + 16];
      }
      out[(size_t)(c0 + r) * R + r0 + tx] = (_Float16)va;
      out[(size_t)(c0 + r + 16) * R + r0 + tx] = (_Float16)vb;
    }
  }
  g.sync();

  int br, bc, hf;
  // ---- C1: [q | betas2] = x @ Bcat  (N=2048, K=2048) ----
  map32(bid, br, bc);
  gtile<EPI_SPLIT, false>(x_h, 2048, Bcat, 2048, 0, 32, 2048, br << 6, bc << 6,
                          nullptr, nullptr, nullptr, nullptr, nullptr, q_h,
                          be2_h, nullptr, sm, tid);
  g.sync();
  // ---- betas = q @ kt0r  (N=1024, K=1024, grid-Ksplit-2 -> Pa) ----
  map16(bid, br, bc, hf);
  gtile<EPI_PART, false>(q_h, 1024, kt0r, 1024, hf << 9, 8, 1024, br << 6,
                         bc << 6, nullptr, nullptr, nullptr, nullptr,
                         hf ? Pa1 : Pa0, nullptr, nullptr, nullptr, sm, tid);
  g.sync();
  // ---- yb = betas @ V0  (RSA from Pa; N=1024, Ksplit-2 -> Pb) ----
  gtile<EPI_PART, true>(nullptr, 0, vt0T, 1024, hf << 9, 8, 1024, br << 6,
                        bc << 6, Pa0, Pa1, nullptr, nullptr, hf ? Pb1 : Pb0,
                        nullptr, nullptr, nullptr, sm, tid);
  g.sync();
  // ---- z0 = yb @ Ve^T, z1 = soft(z0)  (RSA from Pb; N=2048, K=1024) ----
  map32(bid, br, bc);
  gtile<EPI_SOFT, true>(nullptr, 0, ve_h, 1024, 0, 16, 2048, br << 6, bc << 6,
                        Pb0, Pb1, z0_f, z_f, nullptr, zh, nullptr, nullptr, sm,
                        tid);
  g.sync();
  // ---- ISTA iters 2..5 ----
  for (int it = 0; it < 4; ++it) {
    int cr, cc, ch;
    map16(bid, cr, cc, ch);
    // c = z @ Ve  (N=1024, K=2048, Ksplit-2 -> Pa)
    gtile<EPI_PART, false>(zh, 2048, ve_hT, 2048, ch << 10, 16, 1024, cr << 6,
                           cc << 6, nullptr, nullptr, nullptr, nullptr,
                           ch ? Pa1 : Pa0, nullptr, nullptr, nullptr, sm, tid);
    g.sync();
    // z = soft(z0 + z - c@Ve^T)  (RSA from Pa; N=2048, K=1024)
    gtile<EPI_ZUP, true>(nullptr, 0, ve_h, 1024, 0, 16, 2048, br << 6, bc << 6,
                         Pa0, Pa1, z0_f, z_f, nullptr, zh, nullptr, nullptr,
                         sm, tid);
    g.sync();
  }
  // ---- final: y = z + betas2 @ V1^T  (N=2048, K=1024) -> f32 d_out ----
  gtile<EPI_FINAL, false>(be2_h, 1024, vt1_h, 1024, 0, 16, 2048, br << 6,
                          bc << 6, nullptr, nullptr, nullptr, z_f, nullptr,
                          nullptr, nullptr, p.out, sm, tid);
}

// ---------------------------------------------------------------------------
extern "C" void kernel_launch(void* const* d_in, const int* in_sizes, int n_in,
                              void* d_out, int out_size, void* d_ws,
                              size_t ws_size, hipStream_t stream) {
  (void)in_sizes;
  (void)n_in;
  (void)out_size;
  (void)ws_size;
  KP p;
  p.x = (const float*)d_in[0];
  p.ke = (const float*)d_in[1];
  p.ve = (const float*)d_in[2];
  p.k0 = (const float*)d_in[3];
  p.v0 = (const float*)d_in[4];
  p.s0 = (const float*)d_in[5];
  p.k1 = (const float*)d_in[6];
  p.v1 = (const float*)d_in[7];
  p.s1 = (const float*)d_in[8];
  p.out = (float*)d_out;
  p.ws = (_Float16*)d_ws;
  void* kargs[] = {&p};
  hipLaunchCooperativeKernel(mega, dim3(256), dim3(512), kargs, 0, stream);
}

// Round 6
// 120.713 us; speedup vs baseline: 4.8206x; 4.8206x over previous
//
#include <hip/hip_runtime.h>

// ---------------------------------------------------------------------------
// AMM chain, round 6: R4 dispatch skeleton (serial stream, no coop) with
//   - 4-wave blocks, wave tile 32x64 (0.75 ds_read per MFMA, was 1.0)
//   - 8 dispatches: conv | [Q || C1 || W0] | W0' | C2 | ZQ x3 | ZQ4+final
//   - counted-vmcnt gload_lds pipeline, 4+4 LDS buffers, 1 barrier/K-step
//   - conflict-free scalar reduction scratch
// Math identical to R4 (projector fold, diag-exact Q): expect absmax 0.015625.
// Workspace ~38 MB.
// ---------------------------------------------------------------------------

typedef _Float16 f16x8 __attribute__((ext_vector_type(8)));
typedef _Float16 f16x4 __attribute__((ext_vector_type(4)));
typedef float f32x4 __attribute__((ext_vector_type(4)));

enum { EPI_H, EPI_QOFF, EPI_SPLIT, EPI_SOFT, EPI_ZQ, EPI_ZQF, EPI_FINAL };

typedef const __attribute__((address_space(1))) void* gas_ptr;
typedef __attribute__((address_space(3))) void* las_ptr;

__device__ __forceinline__ void gload16(const void* g, void* l) {
  __builtin_amdgcn_global_load_lds((gas_ptr)g, (las_ptr)l, 16, 0, 0);
}

__device__ __forceinline__ float softt(float t) {
  float s = fabsf(t) - 1.0f;
  s = s > 0.0f ? s : 0.0f;
  return copysignf(s, t);
}

// ---------------------------------------------------------------------------
// unified conversion kernel (R4-proven). block (32,8).
// z=0..3 transposing f32->f16 (optional scale); z=4 plain f32->f16 x3.
// ---------------------------------------------------------------------------
__global__ __launch_bounds__(256) void convAll(
    const float* __restrict__ e0, const float* __restrict__ e1,
    const float* __restrict__ e2, const float* __restrict__ e3,
    _Float16* __restrict__ o0, _Float16* __restrict__ o1,
    _Float16* __restrict__ o2, _Float16* __restrict__ o3,
    const float* __restrict__ s1, const float* __restrict__ s2,
    const float4* __restrict__ pa, f16x4* __restrict__ qa, int na,
    const float4* __restrict__ pb, f16x4* __restrict__ qb, int nb,
    const float4* __restrict__ pc, f16x4* __restrict__ qc, int nc) {
  const int z = blockIdx.z;
  if (z == 4) {
    const int total = na + nb + nc;
    const int bid = blockIdx.y * 32 + blockIdx.x;
    const int nthr = 2048 * 256;
    for (int i = bid * 256 + threadIdx.y * 32 + threadIdx.x; i < total;
         i += nthr) {
      const float4* s;
      f16x4* d;
      int j = i;
      if (j < na) {
        s = pa; d = qa;
      } else if ((j -= na) < nb) {
        s = pb; d = qb;
      } else {
        j -= nb; s = pc; d = qc;
      }
      float4 v = s[j];
      f16x4 h = {(_Float16)v.x, (_Float16)v.y, (_Float16)v.z, (_Float16)v.w};
      d[j] = h;
    }
    return;
  }
  const float* in = z == 0 ? e0 : z == 1 ? e1 : z == 2 ? e2 : e3;
  _Float16* out = z == 0 ? o0 : z == 1 ? o1 : z == 2 ? o2 : o3;
  const int R = (z < 2) ? 2048 : 1024;
  const int C = 1024;
  const int mode = z == 1 ? 1 : z == 2 ? 2 : 0;
  const float* sv = z == 1 ? s1 : s2;
  __shared__ float t[32][33];
  const int tx = threadIdx.x, ty = threadIdx.y;
  const int c0 = blockIdx.x * 32, r0 = blockIdx.y * 32;
  if (r0 >= R) return;  // uniform per block
#pragma unroll
  for (int i = 0; i < 32; i += 8)
    t[ty + i][tx] = in[(size_t)(r0 + ty + i) * C + c0 + tx];
  __syncthreads();
#pragma unroll
  for (int i = 0; i < 32; i += 8) {
    float v = t[tx][ty + i];
    if (mode == 1) v *= sv[c0 + ty + i];
    if (mode == 2) v *= sv[r0 + tx];
    out[(size_t)(c0 + ty + i) * R + r0 + tx] = (_Float16)v;
  }
}

// ---------------------------------------------------------------------------
// 64x64 output tile, NT: C[m,n] = sum_k A[m,k]*B[n,k]. fp16 in, f32 accum.
// 256 thr = 4 waves: wr = w&1 (M half), wk = w>>1 (K half of each 64-step).
// Wave tile 32x64: 2(mi) x 4(ni) frags of 16x16x32 MFMA; 6 ds_read_b128 per
// 8 MFMA. Staging: gload_lds, 4 A-bufs + 4 B-bufs (8KB each, 64KB total),
// issue-ahead 2, vmcnt(8/4/0), one s_barrier per K-step.
// LDS swizzle: row r, chunk c (8 halfs) at r*64 + ((c ^ (r&7))*8), staged
// linearly with pre-swizzled global source chunk.
// ---------------------------------------------------------------------------
template <int EPI>
__device__ __forceinline__ void gtile(
    const _Float16* __restrict__ A, int lda, const _Float16* __restrict__ B,
    int ldb, int nK, int N, int brow, int bcol, const float* __restrict__ dgv,
    float* __restrict__ dgout, float* __restrict__ fA, float* __restrict__ fB,
    _Float16* __restrict__ oh, _Float16* __restrict__ oh2,
    float* __restrict__ ofin, _Float16* sm, int tid) {
  const int lane = tid & 63;
  const int w = tid >> 6;      // 0..3
  const int wr = w & 1;        // M half
  const int wk = w >> 1;       // K half within 64-step
  const int srow = lane >> 3;
  const int scol = ((lane & 7) ^ srow) << 3;  // pre-swizzled source chunk
  const int a15 = lane & 15;
  const int hi = lane >> 4;    // 0..3
  const int l7 = lane & 7;

  const _Float16* apg = A + (size_t)(brow + (w << 4) + srow) * lda + scol;
  const _Float16* bpg = B + (size_t)(bcol + (w << 4) + srow) * ldb + scol;
  _Float16* AB = sm;              // 4 x 4096 halfs
  _Float16* BB = sm + 16384;      // 4 x 4096 halfs
  const int ldstA = w << 10;      // wave stages rows [16w,16w+16)

  const int ca = ((wk << 2) + hi) ^ l7;
  int raddr[2], baddr[4];
#pragma unroll
  for (int mi = 0; mi < 2; ++mi)
    raddr[mi] = ((wr << 5) + (mi << 4) + a15) * 64 + (ca << 3);
#pragma unroll
  for (int ni = 0; ni < 4; ++ni)
    baddr[ni] = ((ni << 4) + a15) * 64 + (ca << 3);

  f32x4 acc[2][4] = {};

  __syncthreads();  // LDS handoff from previous phase

#pragma unroll
  for (int p = 0; p < 2; ++p) {
    gload16(apg + p * 64, AB + p * 4096 + ldstA);
    gload16(apg + p * 64 + (size_t)8 * lda, AB + p * 4096 + ldstA + 512);
    gload16(bpg + p * 64, BB + p * 4096 + ldstA);
    gload16(bpg + p * 64 + (size_t)8 * ldb, BB + p * 4096 + ldstA + 512);
  }

  for (int kt = 0; kt < nK; ++kt) {
    if (kt + 2 < nK) {
      const int bf = (kt + 2) & 3;
      const int co = (kt + 2) << 6;
      gload16(apg + co, AB + bf * 4096 + ldstA);
      gload16(apg + co + (size_t)8 * lda, AB + bf * 4096 + ldstA + 512);
      gload16(bpg + co, BB + bf * 4096 + ldstA);
      gload16(bpg + co + (size_t)8 * ldb, BB + bf * 4096 + ldstA + 512);
    }
    const int rem = nK - 1 - kt;
    if (rem >= 2)
      asm volatile("s_waitcnt vmcnt(8)" ::: "memory");
    else if (rem == 1)
      asm volatile("s_waitcnt vmcnt(4)" ::: "memory");
    else
      asm volatile("s_waitcnt vmcnt(0)" ::: "memory");
    __builtin_amdgcn_s_barrier();
    __builtin_amdgcn_sched_barrier(0);
    const _Float16* Ab = AB + (kt & 3) * 4096;
    const _Float16* Bb = BB + (kt & 3) * 4096;
    f16x8 av[2], bv[4];
    av[0] = *(const f16x8*)(Ab + raddr[0]);
    av[1] = *(const f16x8*)(Ab + raddr[1]);
    bv[0] = *(const f16x8*)(Bb + baddr[0]);
    bv[1] = *(const f16x8*)(Bb + baddr[1]);
    bv[2] = *(const f16x8*)(Bb + baddr[2]);
    bv[3] = *(const f16x8*)(Bb + baddr[3]);
#pragma unroll
    for (int mi = 0; mi < 2; ++mi)
#pragma unroll
      for (int ni = 0; ni < 4; ++ni)
        acc[mi][ni] = __builtin_amdgcn_mfma_f32_16x16x32_f16(
            av[mi], bv[ni], acc[mi][ni], 0, 0, 0);
  }

  // cross-K (wk) reduction; conflict-free scalar scratch scr[c][128]
  __syncthreads();
  float* scr = (float*)sm;
  const int sl = (wr << 6) + lane;
  if (wk == 1) {
#pragma unroll
    for (int mi = 0; mi < 2; ++mi)
#pragma unroll
      for (int ni = 0; ni < 4; ++ni)
#pragma unroll
        for (int r = 0; r < 4; ++r)
          scr[(((mi << 2) + ni) * 4 + r) * 128 + sl] = acc[mi][ni][r];
  }
  __syncthreads();
  if (wk == 0) {
#pragma unroll
    for (int mi = 0; mi < 2; ++mi) {
#pragma unroll
      for (int ni = 0; ni < 4; ++ni) {
#pragma unroll
        for (int r = 0; r < 4; ++r) {
          const float v =
              acc[mi][ni][r] + scr[(((mi << 2) + ni) * 4 + r) * 128 + sl];
          const int row = brow + (wr << 5) + (mi << 4) + (hi << 2) + r;
          const int col = bcol + (ni << 4) + a15;
          const size_t idx = (size_t)row * N + col;
          if constexpr (EPI == EPI_H) {
            oh[idx] = (_Float16)v;
          } else if constexpr (EPI == EPI_QOFF) {
            if (row == col) {
              dgout[row] = 1.0f - v;
              oh[idx] = (_Float16)0.0f;
            } else {
              oh[idx] = (_Float16)(-v);
            }
          } else if constexpr (EPI == EPI_SPLIT) {
            if (col < 1024)
              oh[(size_t)row * 1024 + col] = (_Float16)v;
            else
              oh2[(size_t)row * 1024 + (col - 1024)] = (_Float16)v;
          } else if constexpr (EPI == EPI_SOFT) {
            fA[idx] = v;
            float s = softt(v);
            fB[idx] = s;
            oh[idx] = (_Float16)s;
          } else if constexpr (EPI == EPI_ZQ) {
            float t = fA[idx] + dgv[col] * fB[idx] + v;
            float s = softt(t);
            fB[idx] = s;
            oh[idx] = (_Float16)s;
          } else if constexpr (EPI == EPI_ZQF) {
            float t = fA[idx] + dgv[col] * fB[idx] + v;
            fB[idx] = softt(t);
          } else {  // EPI_FINAL
            ofin[idx] = fB[idx] + v;
          }
        }
      }
    }
  }
}

// ---------------------------------------------------------------------------
// wrappers
// ---------------------------------------------------------------------------
struct WS {
  const _Float16 *ve, *vt1, *w0pT_r, *Bcat, *qoff_r, *x, *kt0s, *vt0T, *w0_r,
      *q_r, *be2;
  _Float16 *w0pT_w, *qoff_w, *w0_w, *q_w, *be2_w, *zhA, *zhB;
  float *z0, *zf, *dg;
};

__global__ __launch_bounds__(256, 2) void kD2(WS p) {
  __shared__ __align__(16) _Float16 sm[32768];
  const int tid = threadIdx.x;
  const int bid = blockIdx.x;
  if (bid < 1024) {  // Q = I - Ve Ve^T (2048x2048, K=1024)
    gtile<EPI_QOFF>(p.ve, 1024, p.ve, 1024, 16, 2048, (bid >> 5) << 6,
                    (bid & 31) << 6, nullptr, p.dg, nullptr, nullptr, p.qoff_w,
                    nullptr, nullptr, sm, tid);
  } else if (bid < 1280) {  // C1: [q|betas2] = x @ Bcat (512x2048, K=2048)
    const int i = bid - 1024;
    gtile<EPI_SPLIT>(p.x, 2048, p.Bcat, 2048, 32, 2048, (i >> 5) << 6,
                     (i & 31) << 6, nullptr, nullptr, nullptr, nullptr, p.q_w,
                     p.be2_w, nullptr, sm, tid);
  } else {  // W0 = (K0^T s0) @ V0 (1024x1024, K=1024)
    const int i = bid - 1280;
    gtile<EPI_H>(p.kt0s, 1024, p.vt0T, 1024, 16, 1024, (i >> 4) << 6,
                 (i & 15) << 6, nullptr, nullptr, nullptr, nullptr, p.w0_w,
                 nullptr, nullptr, sm, tid);
  }
}

__global__ __launch_bounds__(256, 2) void kW0p(WS p) {
  __shared__ __align__(16) _Float16 sm[32768];
  const int bid = blockIdx.x;  // 512 blocks: W0' = Ve @ W0^T (2048x1024)
  gtile<EPI_H>(p.ve, 1024, p.w0_r, 1024, 16, 1024, (bid >> 4) << 6,
               (bid & 15) << 6, nullptr, nullptr, nullptr, nullptr, p.w0pT_w,
               nullptr, nullptr, sm, threadIdx.x);
}

__global__ __launch_bounds__(256, 2) void kC2(WS p) {
  __shared__ __align__(16) _Float16 sm[32768];
  const int bid = blockIdx.x;  // 256: z0 = q @ W0'^T (512x2048), soft fused
  gtile<EPI_SOFT>(p.q_r, 1024, p.w0pT_r, 1024, 16, 2048, (bid >> 5) << 6,
                  (bid & 31) << 6, nullptr, nullptr, p.z0, p.zf, p.zhA,
                  nullptr, nullptr, sm, threadIdx.x);
}

template <bool AB>
__global__ __launch_bounds__(256, 2) void kZQ(WS p) {
  __shared__ __align__(16) _Float16 sm[32768];
  const int bid = blockIdx.x;  // 256: z = soft(z0 + dg*z + z@Qoff)
  gtile<EPI_ZQ>(AB ? p.zhA : p.zhB, 2048, p.qoff_r, 2048, 32, 2048,
                (bid >> 5) << 6, (bid & 31) << 6, p.dg, nullptr, p.z0, p.zf,
                AB ? p.zhB : p.zhA, nullptr, nullptr, sm, threadIdx.x);
}

__global__ __launch_bounds__(256, 2) void kZQF(WS p, float* out) {
  __shared__ __align__(16) _Float16 sm[32768];
  const int bid = blockIdx.x;  // 256: last ZQ (zf only) + final y
  const int brow = (bid >> 5) << 6, bcol = (bid & 31) << 6;
  gtile<EPI_ZQF>(p.zhB, 2048, p.qoff_r, 2048, 32, 2048, brow, bcol, p.dg,
                 nullptr, p.z0, p.zf, nullptr, nullptr, nullptr, sm,
                 threadIdx.x);
  gtile<EPI_FINAL>(p.be2, 1024, p.vt1, 1024, 16, 2048, brow, bcol, nullptr,
                   nullptr, nullptr, p.zf, nullptr, nullptr, out, sm,
                   threadIdx.x);
}

// ---------------------------------------------------------------------------
extern "C" void kernel_launch(void* const* d_in, const int* in_sizes, int n_in,
                              void* d_out, int out_size, void* d_ws,
                              size_t ws_size, hipStream_t stream) {
  const float* x = (const float*)d_in[0];          // (512,2048)
  const float* key_enc = (const float*)d_in[1];    // (2048,1024)
  const float* val_enc = (const float*)d_in[2];    // (2048,1024)
  const float* keys_t0 = (const float*)d_in[3];    // (1024,1024)
  const float* vals_t0 = (const float*)d_in[4];    // (1024,1024)
  const float* scales_t0 = (const float*)d_in[5];  // (1024,)
  const float* keys_t1 = (const float*)d_in[6];    // (2048,1024)
  const float* vals_t1 = (const float*)d_in[7];    // (2048,1024)
  const float* scales_t1 = (const float*)d_in[8];  // (1024,)

  // workspace (halfs offsets; 1M = 1048576). ~38 MB.
  constexpr size_t M1 = 1048576;
  _Float16* ws = (_Float16*)d_ws;
  _Float16* ve_h = ws;                  // [0,2M)   Ve f16 (reads D2,D3)
  _Float16* vt1_h = ws + 2 * M1;        // [2M,4M)  vals_t1 (D8)
  _Float16* w0pT = ws + 4 * M1;         // [4M,6M)  W0' (D3 out, D4 B)
  _Float16* Bcat = ws + 6 * M1;         // [6M,10M) conv out, D2-C1 B
  _Float16* zhA = ws + 6 * M1;          //   overlay post-D2 (1M)
  float* z0_f = (float*)(ws + 7 * M1);  //   overlay post-D2 (2M halfs)
  _Float16* zhB = ws + 9 * M1;          //   overlay post-D2 (1M)
  _Float16* qoff = ws + 10 * M1;        // [10M,14M) Q off-diag (D2 out)
  _Float16* x_h = ws + 14 * M1;         // [14M,15M) conv out, D2-C1 A
  _Float16* kt0s = ws + 15 * M1;        // [15M,16M) conv out, D2-W0 A
  float* z_f = (float*)(ws + 15 * M1);  //   overlay post-D2 (2M halfs)
  _Float16* vt0T = ws + 16 * M1;        // [16M,17M) conv out, D2-W0 B
  _Float16* w0 = ws + 17 * M1;          // [17M,18M) D2-W0 out, D3 B
  _Float16* q_h = ws + 18 * M1;         // [18M,18.5M)
  _Float16* be2 = ws + 18 * M1 + 524288;  // [18.5M,19M)
  float* dg = (float*)(ws + 19 * M1);   // 2048 f32

  WS p;
  p.ve = ve_h; p.vt1 = vt1_h; p.w0pT_r = w0pT; p.w0pT_w = w0pT;
  p.Bcat = Bcat; p.qoff_r = qoff; p.qoff_w = qoff; p.x = x_h;
  p.kt0s = kt0s; p.vt0T = vt0T; p.w0_r = w0; p.w0_w = w0;
  p.q_r = q_h; p.q_w = q_h; p.be2 = be2; p.be2_w = be2;
  p.zhA = zhA; p.zhB = zhB; p.z0 = z0_f; p.zf = z_f; p.dg = dg;

  // D1: conversions
  convAll<<<dim3(32, 64, 5), dim3(32, 8), 0, stream>>>(
      key_enc, keys_t1, keys_t0, vals_t0, Bcat, Bcat + 2 * M1, kt0s, vt0T,
      scales_t1, scales_t0, (const float4*)x, (f16x4*)x_h, 262144,
      (const float4*)val_enc, (f16x4*)ve_h, 524288, (const float4*)vals_t1,
      (f16x4*)vt1_h, 524288);
  // D2: Q || C1 || W0
  kD2<<<1536, 256, 0, stream>>>(p);
  // D3: W0' = Ve @ W0^T
  kW0p<<<512, 256, 0, stream>>>(p);
  // D4: z0 = q @ W0' (soft fused) -> z0_f, z_f, zhA
  kC2<<<256, 256, 0, stream>>>(p);
  // D5-D7: ISTA iters 2..4 (zh ping-pong)
  kZQ<true><<<256, 256, 0, stream>>>(p);    // zhA -> zhB
  kZQ<false><<<256, 256, 0, stream>>>(p);   // zhB -> zhA
  kZQ<true><<<256, 256, 0, stream>>>(p);    // zhA -> zhB
  // D8: ISTA iter 5 (zf only) + final y = z + betas2 @ V1^T
  kZQF<<<256, 256, 0, stream>>>(p, (float*)d_out);
}

// Round 7
// 110.261 us; speedup vs baseline: 5.2776x; 1.0948x over previous
//
#include <hip/hip_runtime.h>

// ---------------------------------------------------------------------------
// AMM chain, round 7: R6 skeleton + 32x64 tiles (512-block grids, 2 blk/CU)
// for the M=512 iteration chain (z0, ZQ x3, ZQF+final). D2/D3 keep 64^2.
//   dispatches: conv | [Q || C1 || W0] | W0' | z0 | ZQ x3 | ZQF+final
// fp16 MFMA f32-accum, XOR-swizzled LDS, gload_lds counted-vmcnt pipelines.
// Math identical to R4/R6 (projector fold, diag-exact Q): absmax 0.015625.
// ---------------------------------------------------------------------------

typedef _Float16 f16x8 __attribute__((ext_vector_type(8)));
typedef _Float16 f16x4 __attribute__((ext_vector_type(4)));
typedef float f32x4 __attribute__((ext_vector_type(4)));

enum { EPI_H, EPI_QOFF, EPI_SPLIT, EPI_SOFT, EPI_ZQ, EPI_ZQF, EPI_FINAL };

typedef const __attribute__((address_space(1))) void* gas_ptr;
typedef __attribute__((address_space(3))) void* las_ptr;

__device__ __forceinline__ void gload16(const void* g, void* l) {
  __builtin_amdgcn_global_load_lds((gas_ptr)g, (las_ptr)l, 16, 0, 0);
}

__device__ __forceinline__ float softt(float t) {
  float s = fabsf(t) - 1.0f;
  s = s > 0.0f ? s : 0.0f;
  return copysignf(s, t);
}

// ---------------------------------------------------------------------------
// unified conversion kernel (proven). block (32,8).
// z=0..3 transposing f32->f16 (optional scale); z=4 plain f32->f16 x3.
// ---------------------------------------------------------------------------
__global__ __launch_bounds__(256) void convAll(
    const float* __restrict__ e0, const float* __restrict__ e1,
    const float* __restrict__ e2, const float* __restrict__ e3,
    _Float16* __restrict__ o0, _Float16* __restrict__ o1,
    _Float16* __restrict__ o2, _Float16* __restrict__ o3,
    const float* __restrict__ s1, const float* __restrict__ s2,
    const float4* __restrict__ pa, f16x4* __restrict__ qa, int na,
    const float4* __restrict__ pb, f16x4* __restrict__ qb, int nb,
    const float4* __restrict__ pc, f16x4* __restrict__ qc, int nc) {
  const int z = blockIdx.z;
  if (z == 4) {
    const int total = na + nb + nc;
    const int bid = blockIdx.y * 32 + blockIdx.x;
    const int nthr = 2048 * 256;
    for (int i = bid * 256 + threadIdx.y * 32 + threadIdx.x; i < total;
         i += nthr) {
      const float4* s;
      f16x4* d;
      int j = i;
      if (j < na) {
        s = pa; d = qa;
      } else if ((j -= na) < nb) {
        s = pb; d = qb;
      } else {
        j -= nb; s = pc; d = qc;
      }
      float4 v = s[j];
      f16x4 h = {(_Float16)v.x, (_Float16)v.y, (_Float16)v.z, (_Float16)v.w};
      d[j] = h;
    }
    return;
  }
  const float* in = z == 0 ? e0 : z == 1 ? e1 : z == 2 ? e2 : e3;
  _Float16* out = z == 0 ? o0 : z == 1 ? o1 : z == 2 ? o2 : o3;
  const int R = (z < 2) ? 2048 : 1024;
  const int C = 1024;
  const int mode = z == 1 ? 1 : z == 2 ? 2 : 0;
  const float* sv = z == 1 ? s1 : s2;
  __shared__ float t[32][33];
  const int tx = threadIdx.x, ty = threadIdx.y;
  const int c0 = blockIdx.x * 32, r0 = blockIdx.y * 32;
  if (r0 >= R) return;  // uniform per block
#pragma unroll
  for (int i = 0; i < 32; i += 8)
    t[ty + i][tx] = in[(size_t)(r0 + ty + i) * C + c0 + tx];
  __syncthreads();
#pragma unroll
  for (int i = 0; i < 32; i += 8) {
    float v = t[tx][ty + i];
    if (mode == 1) v *= sv[c0 + ty + i];
    if (mode == 2) v *= sv[r0 + tx];
    out[(size_t)(c0 + ty + i) * R + r0 + tx] = (_Float16)v;
  }
}

// ---------------------------------------------------------------------------
// 64x64 tile, NT, 4 waves (wr=M-half, wk=K-half), wave tile 32x64.
// gload_lds 4+4 bufs, ahead 2, vmcnt(8/4/0), 1 barrier/K-step.  [R6-proven]
// ---------------------------------------------------------------------------
template <int EPI>
__device__ __forceinline__ void gtile(
    const _Float16* __restrict__ A, int lda, const _Float16* __restrict__ B,
    int ldb, int nK, int N, int brow, int bcol, const float* __restrict__ dgv,
    float* __restrict__ dgout, float* __restrict__ fA, float* __restrict__ fB,
    _Float16* __restrict__ oh, _Float16* __restrict__ oh2,
    float* __restrict__ ofin, _Float16* sm, int tid) {
  const int lane = tid & 63;
  const int w = tid >> 6;
  const int wr = w & 1;
  const int wk = w >> 1;
  const int srow = lane >> 3;
  const int scol = ((lane & 7) ^ srow) << 3;
  const int a15 = lane & 15;
  const int hi = lane >> 4;
  const int l7 = lane & 7;

  const _Float16* apg = A + (size_t)(brow + (w << 4) + srow) * lda + scol;
  const _Float16* bpg = B + (size_t)(bcol + (w << 4) + srow) * ldb + scol;
  _Float16* AB = sm;
  _Float16* BB = sm + 16384;
  const int ldstA = w << 10;

  const int ca = ((wk << 2) + hi) ^ l7;
  int raddr[2], baddr[4];
#pragma unroll
  for (int mi = 0; mi < 2; ++mi)
    raddr[mi] = ((wr << 5) + (mi << 4) + a15) * 64 + (ca << 3);
#pragma unroll
  for (int ni = 0; ni < 4; ++ni)
    baddr[ni] = ((ni << 4) + a15) * 64 + (ca << 3);

  f32x4 acc[2][4] = {};

  __syncthreads();

#pragma unroll
  for (int p = 0; p < 2; ++p) {
    gload16(apg + p * 64, AB + p * 4096 + ldstA);
    gload16(apg + p * 64 + (size_t)8 * lda, AB + p * 4096 + ldstA + 512);
    gload16(bpg + p * 64, BB + p * 4096 + ldstA);
    gload16(bpg + p * 64 + (size_t)8 * ldb, BB + p * 4096 + ldstA + 512);
  }

  for (int kt = 0; kt < nK; ++kt) {
    if (kt + 2 < nK) {
      const int bf = (kt + 2) & 3;
      const int co = (kt + 2) << 6;
      gload16(apg + co, AB + bf * 4096 + ldstA);
      gload16(apg + co + (size_t)8 * lda, AB + bf * 4096 + ldstA + 512);
      gload16(bpg + co, BB + bf * 4096 + ldstA);
      gload16(bpg + co + (size_t)8 * ldb, BB + bf * 4096 + ldstA + 512);
    }
    const int rem = nK - 1 - kt;
    if (rem >= 2)
      asm volatile("s_waitcnt vmcnt(8)" ::: "memory");
    else if (rem == 1)
      asm volatile("s_waitcnt vmcnt(4)" ::: "memory");
    else
      asm volatile("s_waitcnt vmcnt(0)" ::: "memory");
    __builtin_amdgcn_s_barrier();
    __builtin_amdgcn_sched_barrier(0);
    const _Float16* Ab = AB + (kt & 3) * 4096;
    const _Float16* Bb = BB + (kt & 3) * 4096;
    f16x8 av[2], bv[4];
    av[0] = *(const f16x8*)(Ab + raddr[0]);
    av[1] = *(const f16x8*)(Ab + raddr[1]);
    bv[0] = *(const f16x8*)(Bb + baddr[0]);
    bv[1] = *(const f16x8*)(Bb + baddr[1]);
    bv[2] = *(const f16x8*)(Bb + baddr[2]);
    bv[3] = *(const f16x8*)(Bb + baddr[3]);
#pragma unroll
    for (int mi = 0; mi < 2; ++mi)
#pragma unroll
      for (int ni = 0; ni < 4; ++ni)
        acc[mi][ni] = __builtin_amdgcn_mfma_f32_16x16x32_f16(
            av[mi], bv[ni], acc[mi][ni], 0, 0, 0);
  }

  __syncthreads();
  float* scr = (float*)sm;
  const int sl = (wr << 6) + lane;
  if (wk == 1) {
#pragma unroll
    for (int mi = 0; mi < 2; ++mi)
#pragma unroll
      for (int ni = 0; ni < 4; ++ni)
#pragma unroll
        for (int r = 0; r < 4; ++r)
          scr[(((mi << 2) + ni) * 4 + r) * 128 + sl] = acc[mi][ni][r];
  }
  __syncthreads();
  if (wk == 0) {
#pragma unroll
    for (int mi = 0; mi < 2; ++mi) {
#pragma unroll
      for (int ni = 0; ni < 4; ++ni) {
#pragma unroll
        for (int r = 0; r < 4; ++r) {
          const float v =
              acc[mi][ni][r] + scr[(((mi << 2) + ni) * 4 + r) * 128 + sl];
          const int row = brow + (wr << 5) + (mi << 4) + (hi << 2) + r;
          const int col = bcol + (ni << 4) + a15;
          const size_t idx = (size_t)row * N + col;
          if constexpr (EPI == EPI_H) {
            oh[idx] = (_Float16)v;
          } else if constexpr (EPI == EPI_QOFF) {
            if (row == col) {
              dgout[row] = 1.0f - v;
              oh[idx] = (_Float16)0.0f;
            } else {
              oh[idx] = (_Float16)(-v);
            }
          } else if constexpr (EPI == EPI_SPLIT) {
            if (col < 1024)
              oh[(size_t)row * 1024 + col] = (_Float16)v;
            else
              oh2[(size_t)row * 1024 + (col - 1024)] = (_Float16)v;
          }
        }
      }
    }
  }
}

// ---------------------------------------------------------------------------
// 32x64 tile, NT, 4 waves (wc=N-half, wk=K-half), wave tile 32x32.
// grid 512 for M=512/N=2048 -> 2 blocks/CU. LDS 48 KB: A 4x4KB + B 4x8KB.
// 3 gloads/wave/step, ahead 2, vmcnt(6/3/0), 1 barrier/K-step.
// ---------------------------------------------------------------------------
template <int EPI>
__device__ __forceinline__ void gt32(
    const _Float16* __restrict__ A, int lda, const _Float16* __restrict__ B,
    int ldb, int nK, int N, int brow, int bcol, const float* __restrict__ dgv,
    float* __restrict__ fA, float* __restrict__ fB,
    _Float16* __restrict__ oh, float* __restrict__ ofin, _Float16* sm,
    int tid) {
  const int lane = tid & 63;
  const int w = tid >> 6;
  const int wc = w & 1;   // N half (32 cols)
  const int wk = w >> 1;  // K half within 64-step
  const int srow = lane >> 3;
  const int scol = ((lane & 7) ^ srow) << 3;
  const int a15 = lane & 15, hi = lane >> 4, l7 = lane & 7;

  const _Float16* apg = A + (size_t)(brow + (w << 3) + srow) * lda + scol;
  const _Float16* bpg = B + (size_t)(bcol + (w << 4) + srow) * ldb + scol;
  _Float16* AB = sm;          // 4 bufs x 2048 halfs
  _Float16* BB = sm + 8192;   // 4 bufs x 4096 halfs
  const int ca = ((wk << 2) + hi) ^ l7;
  int raddr[2], baddr[2];
#pragma unroll
  for (int mi = 0; mi < 2; ++mi)
    raddr[mi] = ((mi << 4) + a15) * 64 + (ca << 3);
#pragma unroll
  for (int ni = 0; ni < 2; ++ni)
    baddr[ni] = ((wc << 5) + (ni << 4) + a15) * 64 + (ca << 3);

  f32x4 acc[2][2] = {};
  __syncthreads();  // LDS handoff

#pragma unroll
  for (int p = 0; p < 2; ++p) {
    gload16(apg + p * 64, AB + p * 2048 + (w << 9));
    gload16(bpg + p * 64, BB + p * 4096 + (w << 10));
    gload16(bpg + p * 64 + (size_t)8 * ldb, BB + p * 4096 + (w << 10) + 512);
  }
  for (int kt = 0; kt < nK; ++kt) {
    if (kt + 2 < nK) {
      const int bf = (kt + 2) & 3;
      const int co = (kt + 2) << 6;
      gload16(apg + co, AB + bf * 2048 + (w << 9));
      gload16(bpg + co, BB + bf * 4096 + (w << 10));
      gload16(bpg + co + (size_t)8 * ldb, BB + bf * 4096 + (w << 10) + 512);
    }
    const int rem = nK - 1 - kt;
    if (rem >= 2)
      asm volatile("s_waitcnt vmcnt(6)" ::: "memory");
    else if (rem == 1)
      asm volatile("s_waitcnt vmcnt(3)" ::: "memory");
    else
      asm volatile("s_waitcnt vmcnt(0)" ::: "memory");
    __builtin_amdgcn_s_barrier();
    __builtin_amdgcn_sched_barrier(0);
    const _Float16* Ab = AB + (kt & 3) * 2048;
    const _Float16* Bb = BB + (kt & 3) * 4096;
    f16x8 av[2], bv[2];
    av[0] = *(const f16x8*)(Ab + raddr[0]);
    av[1] = *(const f16x8*)(Ab + raddr[1]);
    bv[0] = *(const f16x8*)(Bb + baddr[0]);
    bv[1] = *(const f16x8*)(Bb + baddr[1]);
#pragma unroll
    for (int mi = 0; mi < 2; ++mi)
#pragma unroll
      for (int ni = 0; ni < 2; ++ni)
        acc[mi][ni] = __builtin_amdgcn_mfma_f32_16x16x32_f16(
            av[mi], bv[ni], acc[mi][ni], 0, 0, 0);
  }
  __syncthreads();
  float* scr = (float*)sm;
  const int sl = (wc << 6) + lane;
  if (wk == 1) {
#pragma unroll
    for (int mi = 0; mi < 2; ++mi)
#pragma unroll
      for (int ni = 0; ni < 2; ++ni)
#pragma unroll
        for (int r = 0; r < 4; ++r)
          scr[(((mi << 1) + ni) * 4 + r) * 128 + sl] = acc[mi][ni][r];
  }
  __syncthreads();
  if (wk == 0) {
#pragma unroll
    for (int mi = 0; mi < 2; ++mi) {
#pragma unroll
      for (int ni = 0; ni < 2; ++ni) {
#pragma unroll
        for (int r = 0; r < 4; ++r) {
          const float v =
              acc[mi][ni][r] + scr[(((mi << 1) + ni) * 4 + r) * 128 + sl];
          const int row = brow + (mi << 4) + (hi << 2) + r;
          const int col = bcol + (wc << 5) + (ni << 4) + a15;
          const size_t idx = (size_t)row * N + col;
          if constexpr (EPI == EPI_SOFT) {
            fA[idx] = v;
            float s = softt(v);
            fB[idx] = s;
            oh[idx] = (_Float16)s;
          } else if constexpr (EPI == EPI_ZQ) {
            float t = fA[idx] + dgv[col] * fB[idx] + v;
            float s = softt(t);
            fB[idx] = s;
            oh[idx] = (_Float16)s;
          } else if constexpr (EPI == EPI_ZQF) {
            float t = fA[idx] + dgv[col] * fB[idx] + v;
            fB[idx] = softt(t);
          } else {  // EPI_FINAL
            ofin[idx] = fB[idx] + v;
          }
        }
      }
    }
  }
}

// ---------------------------------------------------------------------------
struct WS {
  const _Float16 *ve, *vt1, *w0pT_r, *Bcat, *qoff_r, *x, *kt0s, *vt0T, *w0_r,
      *q_r, *be2;
  _Float16 *w0pT_w, *qoff_w, *w0_w, *q_w, *be2_w, *zhA, *zhB;
  float *z0, *zf, *dg;
};

// 512-block XCD-chunked map for 16(brow32) x 32(bcol64) tiles
__device__ __forceinline__ void map512(int b, int& br, int& bc) {
  const int x = b & 7, i = b >> 3;
  bc = (x << 2) | (i & 3);  // 0..31
  br = i >> 2;              // 0..15
}

__global__ __launch_bounds__(256, 2) void kD2(WS p) {
  __shared__ __align__(16) _Float16 sm[32768];
  const int tid = threadIdx.x;
  const int bid = blockIdx.x;
  if (bid < 1024) {  // Q = I - Ve Ve^T (2048x2048, K=1024)
    gtile<EPI_QOFF>(p.ve, 1024, p.ve, 1024, 16, 2048, (bid >> 5) << 6,
                    (bid & 31) << 6, nullptr, p.dg, nullptr, nullptr, p.qoff_w,
                    nullptr, nullptr, sm, tid);
  } else if (bid < 1280) {  // C1: [q|betas2] = x @ Bcat (512x2048, K=2048)
    const int i = bid - 1024;
    gtile<EPI_SPLIT>(p.x, 2048, p.Bcat, 2048, 32, 2048, (i >> 5) << 6,
                     (i & 31) << 6, nullptr, nullptr, nullptr, nullptr, p.q_w,
                     p.be2_w, nullptr, sm, tid);
  } else {  // W0 = (K0^T s0) @ V0 (1024x1024, K=1024)
    const int i = bid - 1280;
    gtile<EPI_H>(p.kt0s, 1024, p.vt0T, 1024, 16, 1024, (i >> 4) << 6,
                 (i & 15) << 6, nullptr, nullptr, nullptr, nullptr, p.w0_w,
                 nullptr, nullptr, sm, tid);
  }
}

__global__ __launch_bounds__(256, 2) void kW0p(WS p) {
  __shared__ __align__(16) _Float16 sm[32768];
  const int x = blockIdx.x & 7, i = blockIdx.x >> 3;
  const int bc = (x << 1) | (i & 1), br = i >> 1;  // 16 bcol x 32 brow
  gtile<EPI_H>(p.ve, 1024, p.w0_r, 1024, 16, 1024, br << 6, bc << 6, nullptr,
               nullptr, nullptr, nullptr, p.w0pT_w, nullptr, nullptr, sm,
               threadIdx.x);
}

__global__ __launch_bounds__(256, 2) void kC2(WS p) {
  __shared__ __align__(16) _Float16 sm[24576];
  int br, bc;
  map512(blockIdx.x, br, bc);  // z0 = q @ W0'^T (512x2048, K=1024), soft
  gt32<EPI_SOFT>(p.q_r, 1024, p.w0pT_r, 1024, 16, 2048, br << 5, bc << 6,
                 nullptr, p.z0, p.zf, p.zhA, nullptr, sm, threadIdx.x);
}

template <bool AB>
__global__ __launch_bounds__(256, 2) void kZQ(WS p) {
  __shared__ __align__(16) _Float16 sm[24576];
  int br, bc;
  map512(blockIdx.x, br, bc);  // z = soft(z0 + dg*z + z@Qoff)
  gt32<EPI_ZQ>(AB ? p.zhA : p.zhB, 2048, p.qoff_r, 2048, 32, 2048, br << 5,
               bc << 6, p.dg, p.z0, p.zf, AB ? p.zhB : p.zhA, nullptr, sm,
               threadIdx.x);
}

__global__ __launch_bounds__(256, 2) void kZQF(WS p, float* out) {
  __shared__ __align__(16) _Float16 sm[24576];
  int br, bc;
  map512(blockIdx.x, br, bc);  // last ZQ (zf only) + final y
  gt32<EPI_ZQF>(p.zhB, 2048, p.qoff_r, 2048, 32, 2048, br << 5, bc << 6, p.dg,
                p.z0, p.zf, nullptr, nullptr, sm, threadIdx.x);
  gt32<EPI_FINAL>(p.be2, 1024, p.vt1, 1024, 16, 2048, br << 5, bc << 6,
                  nullptr, nullptr, p.zf, nullptr, out, sm, threadIdx.x);
}

// ---------------------------------------------------------------------------
extern "C" void kernel_launch(void* const* d_in, const int* in_sizes, int n_in,
                              void* d_out, int out_size, void* d_ws,
                              size_t ws_size, hipStream_t stream) {
  const float* x = (const float*)d_in[0];          // (512,2048)
  const float* key_enc = (const float*)d_in[1];    // (2048,1024)
  const float* val_enc = (const float*)d_in[2];    // (2048,1024)
  const float* keys_t0 = (const float*)d_in[3];    // (1024,1024)
  const float* vals_t0 = (const float*)d_in[4];    // (1024,1024)
  const float* scales_t0 = (const float*)d_in[5];  // (1024,)
  const float* keys_t1 = (const float*)d_in[6];    // (2048,1024)
  const float* vals_t1 = (const float*)d_in[7];    // (2048,1024)
  const float* scales_t1 = (const float*)d_in[8];  // (1024,)

  // workspace (halfs offsets; 1M = 1048576). ~38 MB.
  constexpr size_t M1 = 1048576;
  _Float16* ws = (_Float16*)d_ws;
  _Float16* ve_h = ws;                  // [0,2M)   Ve f16 (reads D2,D3)
  _Float16* vt1_h = ws + 2 * M1;        // [2M,4M)  vals_t1 (D8)
  _Float16* w0pT = ws + 4 * M1;         // [4M,6M)  W0' (D3 out, D4 B)
  _Float16* Bcat = ws + 6 * M1;         // [6M,10M) conv out, D2-C1 B
  _Float16* zhA = ws + 6 * M1;          //   overlay post-D2 (1M)
  float* z0_f = (float*)(ws + 7 * M1);  //   overlay post-D2 (2M halfs)
  _Float16* zhB = ws + 9 * M1;          //   overlay post-D2 (1M)
  _Float16* qoff = ws + 10 * M1;        // [10M,14M) Q off-diag (D2 out)
  _Float16* x_h = ws + 14 * M1;         // [14M,15M) conv out, D2-C1 A
  _Float16* kt0s = ws + 15 * M1;        // [15M,16M) conv out, D2-W0 A
  float* z_f = (float*)(ws + 15 * M1);  //   overlay post-D2 (2M halfs)
  _Float16* vt0T = ws + 16 * M1;        // [16M,17M) conv out, D2-W0 B
  _Float16* w0 = ws + 17 * M1;          // [17M,18M) D2-W0 out, D3 B
  _Float16* q_h = ws + 18 * M1;         // [18M,18.5M)
  _Float16* be2 = ws + 18 * M1 + 524288;  // [18.5M,19M)
  float* dg = (float*)(ws + 19 * M1);   // 2048 f32

  WS p;
  p.ve = ve_h; p.vt1 = vt1_h; p.w0pT_r = w0pT; p.w0pT_w = w0pT;
  p.Bcat = Bcat; p.qoff_r = qoff; p.qoff_w = qoff; p.x = x_h;
  p.kt0s = kt0s; p.vt0T = vt0T; p.w0_r = w0; p.w0_w = w0;
  p.q_r = q_h; p.q_w = q_h; p.be2 = be2; p.be2_w = be2;
  p.zhA = zhA; p.zhB = zhB; p.z0 = z0_f; p.zf = z_f; p.dg = dg;

  // D1: conversions
  convAll<<<dim3(32, 64, 5), dim3(32, 8), 0, stream>>>(
      key_enc, keys_t1, keys_t0, vals_t0, Bcat, Bcat + 2 * M1, kt0s, vt0T,
      scales_t1, scales_t0, (const float4*)x, (f16x4*)x_h, 262144,
      (const float4*)val_enc, (f16x4*)ve_h, 524288, (const float4*)vals_t1,
      (f16x4*)vt1_h, 524288);
  // D2: Q || C1 || W0
  kD2<<<1536, 256, 0, stream>>>(p);
  // D3: W0' = Ve @ W0^T
  kW0p<<<512, 256, 0, stream>>>(p);
  // D4: z0 = q @ W0' (soft fused) -> z0_f, z_f, zhA
  kC2<<<512, 256, 0, stream>>>(p);
  // D5-D7: ISTA iters 2..4 (zh ping-pong)
  kZQ<true><<<512, 256, 0, stream>>>(p);    // zhA -> zhB
  kZQ<false><<<512, 256, 0, stream>>>(p);   // zhB -> zhA
  kZQ<true><<<512, 256, 0, stream>>>(p);    // zhA -> zhB
  // D8: ISTA iter 5 (zf only) + final y = z + betas2 @ V1^T
  kZQF<<<512, 256, 0, stream>>>(p, (float*)d_out);
}